// Round 7
// baseline (238.921 us; speedup 1.0000x reference)
//
#include <hip/hip_runtime.h>
#include <cstdint>
#include <cstddef>

#define EMBED 1024
#define NHEAD 16
#define HD    64
#define BATCH 2
#define SEQ   2048
#define MROWS (BATCH*SEQ)   // 4096
#define QSCALE 0.1803368801111137f   // log2(e)/8

typedef __bf16 bf16;
typedef __bf16 bf16x8 __attribute__((ext_vector_type(8)));
typedef float  f32x4  __attribute__((ext_vector_type(4)));
typedef unsigned int u32;

#if __has_builtin(__builtin_amdgcn_exp2f)
#define EXP2(x) __builtin_amdgcn_exp2f(x)
#else
#define EXP2(x) exp2f(x)
#endif

typedef const u32 __attribute__((address_space(1)))* gp_t;
typedef u32 __attribute__((address_space(3)))* lp_t;

// async global->LDS, 16B/lane; LDS dest = wave-uniform base + lane*16
__device__ __forceinline__ void g2l16(const void* g, void* l) {
  __builtin_amdgcn_global_load_lds((gp_t)(uintptr_t)g, (lp_t)(u32)(uintptr_t)l, 16, 0, 0);
}

#define MFMA(a, b, c) __builtin_amdgcn_mfma_f32_16x16x32_bf16((a), (b), (c), 0, 0, 0)

// ---------------- all casts fp32 -> bf16, one dispatch ----------------
#define SZX8 ((MROWS*EMBED)/8)   // 524288
#define SZW8 ((EMBED*EMBED)/8)   // 131072

__global__ void cast_all(const float* __restrict__ q, const float* __restrict__ k,
                         const float* __restrict__ v, const float* __restrict__ wq,
                         const float* __restrict__ wk, const float* __restrict__ wv,
                         const float* __restrict__ wo,
                         bf16* xq, bf16* xk, bf16* xv,
                         bf16* wqb, bf16* wkb, bf16* wvb, bf16* wob) {
  int z = blockIdx.y;
  const float* in; bf16* out;
  switch (z) {
    case 0: in = q;  out = xq;  break;
    case 1: in = k;  out = xk;  break;
    case 2: in = v;  out = xv;  break;
    case 3: in = wq; out = wqb; break;
    case 4: in = wk; out = wkb; break;
    case 5: in = wv; out = wvb; break;
    default: in = wo; out = wob; break;
  }
  int n8 = (z < 3) ? SZX8 : SZW8;
  int i = blockIdx.x * blockDim.x + threadIdx.x;
  if (i >= n8) return;
  const float4* p = (const float4*)in;
  float4 a = p[2*i], b = p[2*i+1];
  union { bf16 h[8]; uint4 u; } r;
  r.h[0] = (bf16)a.x; r.h[1] = (bf16)a.y; r.h[2] = (bf16)a.z; r.h[3] = (bf16)a.w;
  r.h[4] = (bf16)b.x; r.h[5] = (bf16)b.y; r.h[6] = (bf16)b.z; r.h[7] = (bf16)b.w;
  ((uint4*)out)[i] = r.u;
}

// ---------------- GEMM core 128x128: C = A @ W^T ----------------------
#define BM 128
#define BN 128
#define BK 32
#define NKI (EMBED/BK)   // 32

__device__ __forceinline__ void gemm_core(
    const bf16* __restrict__ A, const bf16* __restrict__ W,
    bf16* Al, bf16* Bl, f32x4 (&acc)[4][4])
{
  const int tid  = threadIdx.x;
  const int lane = tid & 63, wid = tid >> 6;
  const int quad = lane >> 4, l16 = lane & 15;
  const int wm = wid >> 1, wn = wid & 1;
  const int m0 = blockIdx.y * BM, n0 = blockIdx.x * BN;

  const int R = tid >> 2, Cc = tid & 3;
  const int gcol = (Cc ^ ((R >> 1) & 3)) * 8;          // swizzled source column
  const bf16* Ag = A + (size_t)(m0 + R) * EMBED + gcol;
  const bf16* Bg = W + (size_t)(n0 + R) * EMBED + gcol;
  bf16* AlW = Al + wid * 512;                          // wave's 1KB chunk
  bf16* BlW = Bl + wid * 512;

  g2l16(Ag, AlW);                      g2l16(Ag + (size_t)64*EMBED, AlW + 2048);
  g2l16(Bg, BlW);                      g2l16(Bg + (size_t)64*EMBED, BlW + 2048);
  __syncthreads();

  for (int ki = 0; ki < NKI; ++ki) {
    const int cur = ki & 1;
    if (ki + 1 < NKI) {
      const int nb = cur ^ 1;
      const int k0 = (ki + 1) * BK;
      g2l16(Ag + k0, AlW + nb*4096);
      g2l16(Ag + (size_t)64*EMBED + k0, AlW + nb*4096 + 2048);
      g2l16(Bg + k0, BlW + nb*4096);
      g2l16(Bg + (size_t)64*EMBED + k0, BlW + nb*4096 + 2048);
    }
    const bf16* Ac = Al + cur*4096;
    const bf16* Bc = Bl + cur*4096;
    bf16x8 af[4], bg[4];
#pragma unroll
    for (int i = 0; i < 4; ++i) {
      int ra = wm*64 + i*16 + l16;
      af[i] = *(const bf16x8*)(Ac + ra*32 + ((quad ^ ((ra>>1)&3))*8));
      int rb = wn*64 + i*16 + l16;
      bg[i] = *(const bf16x8*)(Bc + rb*32 + ((quad ^ ((rb>>1)&3))*8));
    }
#pragma unroll
    for (int i = 0; i < 4; ++i)
#pragma unroll
      for (int j = 0; j < 4; ++j)
        acc[i][j] = MFMA(af[i], bg[j], acc[i][j]);
    __syncthreads();
  }
}

// QKV fused: blockIdx.z selects {Q,K,V}. Q scaled by log2(e)/8.
// V written transposed AND pi-permuted per 64-token tile:
// global pos = tile*64 + pi(local), pi(x) = (x&15)*4 + (x>>4).
__global__ __launch_bounds__(256) void qkv_kernel(
    const bf16* __restrict__ Xq, const bf16* __restrict__ Xk, const bf16* __restrict__ Xv,
    const bf16* __restrict__ Wq, const bf16* __restrict__ Wk, const bf16* __restrict__ Wv,
    const float* __restrict__ bq, const float* __restrict__ bk, const float* __restrict__ bv,
    bf16* __restrict__ Qp, bf16* __restrict__ Kp, bf16* __restrict__ VTg)
{
  __shared__ bf16 Al[2*BM*BK];
  __shared__ bf16 Bl[2*BN*BK];
  const int z = blockIdx.z;
  const bf16* A = z==0 ? Xq : z==1 ? Xk : Xv;
  const bf16* W = z==0 ? Wq : z==1 ? Wk : Wv;
  const float* bias = z==0 ? bq : z==1 ? bk : bv;
  const float scale = (z==0) ? QSCALE : 1.0f;

  f32x4 acc[4][4] = {};
  gemm_core(A, W, Al, Bl, acc);

  const int lane = threadIdx.x & 63, wid = threadIdx.x >> 6;
  const int quad = lane >> 4, l16 = lane & 15;
  const int wm = wid >> 1, wn = wid & 1;
  const int m0 = blockIdx.y * BM, n0 = blockIdx.x * BN;

#pragma unroll
  for (int i = 0; i < 4; ++i) {
#pragma unroll
    for (int j = 0; j < 4; ++j) {
      int col = n0 + wn*64 + j*16 + l16;
      float bv2 = bias[col];
      if (z < 2) {
        bf16* outp = (z == 0) ? Qp : Kp;
#pragma unroll
        for (int r = 0; r < 4; ++r) {
          int row = m0 + wm*64 + i*16 + quad*4 + r;
          outp[(size_t)row*EMBED + col] = (bf16)((acc[i][j][r] + bv2) * scale);
        }
      } else {
        int row0 = m0 + wm*64 + i*16 + quad*4;
        int bb = row0 >> 11, ss0 = row0 & (SEQ-1);
        int hh = col >> 6, dd = col & (HD-1);
        const size_t base = (((size_t)bb*NHEAD + hh)*HD + dd)*SEQ;
#pragma unroll
        for (int r = 0; r < 4; ++r) {
          int s = ss0 + r;
          int tile = s >> 6, loc = s & 63;
          int p = ((loc & 15) << 2) | (loc >> 4);   // pi(loc)
          VTg[base + tile*64 + p] = (bf16)(acc[i][j][r] + bv2);
        }
      }
    }
  }
}

// ---------------- O-projection: 128x64 tiles, fp32 out ----------------
__global__ __launch_bounds__(256) void oproj_kernel(
    const bf16* __restrict__ Ctx, const bf16* __restrict__ Wo,
    const float* __restrict__ bo, float* __restrict__ out)
{
  __shared__ bf16 Al[2*128*32];   // 2 x 8KB
  __shared__ bf16 Bl[2*64*32];    // 2 x 4KB
  const int tid  = threadIdx.x;
  const int lane = tid & 63, wid = tid >> 6;
  const int quad = lane >> 4, l16 = lane & 15;
  const int m0 = blockIdx.y * 128, n0 = blockIdx.x * 64;

  const int R = tid >> 2, Cc = tid & 3;
  const int gcol = (Cc ^ ((R >> 1) & 3)) * 8;
  const bf16* Ag = Ctx + (size_t)(m0 + R) * EMBED + gcol;
  const bf16* Bg = Wo  + (size_t)(n0 + R) * EMBED + gcol;
  bf16* AlW = Al + wid * 512;
  bf16* BlW = Bl + wid * 512;

  g2l16(Ag, AlW);  g2l16(Ag + (size_t)64*EMBED, AlW + 2048);
  g2l16(Bg, BlW);
  __syncthreads();

  f32x4 acc[2][4] = {};
  for (int ki = 0; ki < NKI; ++ki) {
    const int cur = ki & 1;
    if (ki + 1 < NKI) {
      const int nb = cur ^ 1;
      const int k0 = (ki + 1) * BK;
      g2l16(Ag + k0, AlW + nb*4096);
      g2l16(Ag + (size_t)64*EMBED + k0, AlW + nb*4096 + 2048);
      g2l16(Bg + k0, BlW + nb*2048);
    }
    const bf16* Ac = Al + cur*4096;
    const bf16* Bc = Bl + cur*2048;
    bf16x8 af[2], bg[4];
#pragma unroll
    for (int u = 0; u < 2; ++u) {
      int ra = wid*32 + u*16 + l16;
      af[u] = *(const bf16x8*)(Ac + ra*32 + ((quad ^ ((ra>>1)&3))*8));
    }
#pragma unroll
    for (int j = 0; j < 4; ++j) {
      int rb = j*16 + l16;
      bg[j] = *(const bf16x8*)(Bc + rb*32 + ((quad ^ ((rb>>1)&3))*8));
    }
#pragma unroll
    for (int u = 0; u < 2; ++u)
#pragma unroll
      for (int j = 0; j < 4; ++j)
        acc[u][j] = MFMA(af[u], bg[j], acc[u][j]);
    __syncthreads();
  }

#pragma unroll
  for (int u = 0; u < 2; ++u)
#pragma unroll
    for (int j = 0; j < 4; ++j) {
      int col = n0 + j*16 + l16;
      float bv = bo[col];
#pragma unroll
      for (int r = 0; r < 4; ++r) {
        int row = m0 + wid*32 + u*16 + quad*4 + r;
        out[(size_t)row*EMBED + col] = (acc[u][j][r] + bv);
      }
    }
}

// ---------------- flash attention, no-max softmax ---------------------
// 512 threads = 8 waves x 16 q-rows (128-row q-tile); 64-key tiles.
// 16 waves/CU (2 blocks) for latency hiding. P pi-packed (b64 writes);
// V^T pi-ordered in global. Double-buffered K/V via global_load_lds.
#define NT  (SEQ/64)
#define PST 72   // P row stride: 144 B rows -> 16B-aligned b128 reads, 2-way max banks

__global__ __launch_bounds__(512, 4) void attn_kernel(
    const bf16* __restrict__ Qp, const bf16* __restrict__ Kp, const bf16* __restrict__ VT,
    const int* __restrict__ pmask, bf16* __restrict__ Ctx)
{
  __shared__ bf16 Kt[2][64*64];    // 16 KB
  __shared__ bf16 Vt[2][64*64];    // 16 KB
  __shared__ bf16 Pl[8][16*PST];   // 18.4 KB

  const int qt = blockIdx.x, h = blockIdx.y, b = blockIdx.z;
  const int tid = threadIdx.x, lane = tid & 63, wid = tid >> 6;
  const int quad = lane >> 4, l16 = lane & 15;
  const int qrow0 = qt*128 + wid*16;

  const size_t qoff = (size_t)(b*SEQ + qrow0 + l16)*EMBED + h*HD;
  bf16x8 qf0 = *(const bf16x8*)(Qp + qoff + quad*8);
  bf16x8 qf1 = *(const bf16x8*)(Qp + qoff + 32 + quad*8);

  int qm[4];
#pragma unroll
  for (int r = 0; r < 4; ++r) qm[r] = pmask[b*SEQ + qrow0 + quad*4 + r];

  bf16 onev = (bf16)1.0f;
  bf16x8 ones = {onev, onev, onev, onev, onev, onev, onev, onev};

  const bf16* Kg  = Kp + (size_t)b*SEQ*EMBED + h*HD;
  const bf16* VTg = VT + (size_t)(b*NHEAD + h)*HD*SEQ;

  const int R = tid >> 3;                 // 0..63 (key idx for K, dim for V)
  const int Cc = tid & 7;
  const int scol = (Cc ^ (R & 7)) * 8;    // swizzled source column

  f32x4 o[4] = {};
  f32x4 lacc = {};

#define STAGE(kt, buf) do {                                              \
    g2l16(Kg + (size_t)((kt)*64 + R)*EMBED + scol, &Kt[buf][0] + wid*512); \
    g2l16(VTg + (size_t)R*SEQ + (kt)*64 + scol,    &Vt[buf][0] + wid*512); \
  } while (0)

  STAGE(0, 0);
  __syncthreads();

  for (int kt = 0; kt < NT; ++kt) {
    const int cur = kt & 1;
    if (kt + 1 < NT) STAGE(kt + 1, cur ^ 1);   // async, lands by next barrier
    const bf16* Kc = &Kt[cur][0];
    const bf16* Vc = &Vt[cur][0];

    // QK^T + mask + exp2, 4 key groups of 16
    f32x4 sg[4];
#pragma unroll
    for (int g = 0; g < 4; ++g) {
      int ra = g*16 + l16, sa = ra & 7;
      bf16x8 kfa = *(const bf16x8*)(Kc + ra*64 + ((quad     ^ sa)*8));
      bf16x8 kfb = *(const bf16x8*)(Kc + ra*64 + (((quad+4) ^ sa)*8));
      int km = pmask[b*SEQ + kt*64 + g*16 + l16];
      f32x4 s = {};
      s = MFMA(qf0, kfa, s);
      s = MFMA(qf1, kfb, s);
#pragma unroll
      for (int r = 0; r < 4; ++r) sg[g][r] = km ? EXP2(s[r]) : 0.0f;
    }

    // pi-packed P store: position l16*4+g -> one b64 per r
#pragma unroll
    for (int r = 0; r < 4; ++r) {
      union { bf16 h[4]; uint2 uu; } pk;
#pragma unroll
      for (int g = 0; g < 4; ++g) pk.h[g] = (bf16)sg[g][r];
      *(uint2*)(&Pl[wid][(quad*4 + r)*PST + l16*4]) = pk.uu;
    }

    // wave-private P: same-wave DS ordering, no barrier needed
    bf16x8 pf0 = *(const bf16x8*)(&Pl[wid][l16*PST + quad*8]);
    bf16x8 pf1 = *(const bf16x8*)(&Pl[wid][l16*PST + 32 + quad*8]);
    lacc = MFMA(pf0, ones, lacc);
    lacc = MFMA(pf1, ones, lacc);
    // PV: V frags (pi-ordered, matching P)
#pragma unroll
    for (int t = 0; t < 4; ++t) {
      int rd = t*16 + l16, sd = rd & 7;
      bf16x8 vf0 = *(const bf16x8*)(Vc + rd*64 + ((quad     ^ sd)*8));
      bf16x8 vf1 = *(const bf16x8*)(Vc + rd*64 + (((quad+4) ^ sd)*8));
      o[t] = MFMA(pf0, vf0, o[t]);
      o[t] = MFMA(pf1, vf1, o[t]);
    }
    __syncthreads();   // prefetch landed + everyone done with cur
  }

  float inv[4];
#pragma unroll
  for (int r = 0; r < 4; ++r)
    inv[r] = (qm[r] && lacc[r] > 0.f) ? 1.0f / lacc[r] : 0.0f;

#pragma unroll
  for (int t = 0; t < 4; ++t)
#pragma unroll
    for (int r = 0; r < 4; ++r) {
      int row = b*SEQ + qrow0 + quad*4 + r;
      Ctx[(size_t)row*EMBED + h*HD + t*16 + l16] = (bf16)(o[t][r] * inv[r]);
    }
}

// ----------------------------------------------------------------------
extern "C" void kernel_launch(void* const* d_in, const int* in_sizes, int n_in,
                              void* d_out, int out_size, void* d_ws, size_t ws_size,
                              hipStream_t stream)
{
  const float* query = (const float*)d_in[0];
  const float* key   = (const float*)d_in[1];
  const float* value = (const float*)d_in[2];
  const int*   pm    = (const int*)d_in[3];
  const float* Wq = (const float*)d_in[4];
  const float* bq = (const float*)d_in[5];
  const float* Wk = (const float*)d_in[6];
  const float* bk = (const float*)d_in[7];
  const float* Wv = (const float*)d_in[8];
  const float* bv = (const float*)d_in[9];
  const float* Wo = (const float*)d_in[10];
  const float* bo = (const float*)d_in[11];
  float* out = (float*)d_out;

  const size_t SZ_X = (size_t)MROWS * EMBED;   // 4M elems
  const size_t SZ_W = (size_t)EMBED * EMBED;   // 1M elems

  bf16* p   = (bf16*)d_ws;
  bf16* Xq  = p; p += SZ_X;
  bf16* Xk  = p; p += SZ_X;
  bf16* Xv  = p; p += SZ_X;
  bf16* Wqb = p; p += SZ_W;
  bf16* Wkb = p; p += SZ_W;
  bf16* Wvb = p; p += SZ_W;
  bf16* Wob = p; p += SZ_W;
  bf16* Qp  = p; p += SZ_X;
  bf16* Kp  = p; p += SZ_X;
  bf16* VTg = p; p += SZ_X;   // V^T: [b][h][d][pi-ordered s]
  bf16* Ctx = p; p += SZ_X;

  dim3 gc((unsigned)(SZX8/256), 7);   // one dispatch for all 7 casts
  cast_all<<<gc, 256, 0, stream>>>(query, key, value, Wq, Wk, Wv, Wo,
                                   Xq, Xk, Xv, Wqb, Wkb, Wvb, Wob);

  dim3 gq(EMBED/BN, MROWS/BM, 3);   // (8, 32, 3)
  qkv_kernel<<<gq, 256, 0, stream>>>(Xq, Xk, Xv, Wqb, Wkb, Wvb, bq, bk, bv, Qp, Kp, VTg);

  dim3 ga(SEQ/128, NHEAD, BATCH);   // (16, 16, 2) = 512 blocks
  attn_kernel<<<ga, 512, 0, stream>>>(Qp, Kp, VTg, pm, Ctx);

  dim3 gg(EMBED/64, MROWS/128);     // (16, 32) = 512 blocks
  oproj_kernel<<<gg, 256, 0, stream>>>(Ctx, Wob, bo, out);
}

// Round 8
// 225.494 us; speedup vs baseline: 1.0595x; 1.0595x over previous
//
#include <hip/hip_runtime.h>
#include <cstdint>
#include <cstddef>

#define EMBED 1024
#define NHEAD 16
#define HD    64
#define BATCH 2
#define SEQ   2048
#define MROWS (BATCH*SEQ)   // 4096
#define QSCALE 0.1803368801111137f   // log2(e)/8

typedef __bf16 bf16;
typedef __bf16 bf16x8 __attribute__((ext_vector_type(8)));
typedef float  f32x4  __attribute__((ext_vector_type(4)));
typedef unsigned int u32;

#if __has_builtin(__builtin_amdgcn_exp2f)
#define EXP2(x) __builtin_amdgcn_exp2f(x)
#else
#define EXP2(x) exp2f(x)
#endif

typedef const u32 __attribute__((address_space(1)))* gp_t;
typedef u32 __attribute__((address_space(3)))* lp_t;

// async global->LDS, 16B/lane; LDS dest = wave-uniform base + lane*16
__device__ __forceinline__ void g2l16(const void* g, void* l) {
  __builtin_amdgcn_global_load_lds((gp_t)(uintptr_t)g, (lp_t)(u32)(uintptr_t)l, 16, 0, 0);
}

#define MFMA(a, b, c) __builtin_amdgcn_mfma_f32_16x16x32_bf16((a), (b), (c), 0, 0, 0)

// ---------------- all casts fp32 -> bf16, one dispatch ----------------
#define SZX8 ((MROWS*EMBED)/8)   // 524288
#define SZW8 ((EMBED*EMBED)/8)   // 131072

__global__ void cast_all(const float* __restrict__ q, const float* __restrict__ k,
                         const float* __restrict__ v, const float* __restrict__ wq,
                         const float* __restrict__ wk, const float* __restrict__ wv,
                         const float* __restrict__ wo,
                         bf16* xq, bf16* xk, bf16* xv,
                         bf16* wqb, bf16* wkb, bf16* wvb, bf16* wob) {
  int z = blockIdx.y;
  const float* in; bf16* out;
  switch (z) {
    case 0: in = q;  out = xq;  break;
    case 1: in = k;  out = xk;  break;
    case 2: in = v;  out = xv;  break;
    case 3: in = wq; out = wqb; break;
    case 4: in = wk; out = wkb; break;
    case 5: in = wv; out = wvb; break;
    default: in = wo; out = wob; break;
  }
  int n8 = (z < 3) ? SZX8 : SZW8;
  int i = blockIdx.x * blockDim.x + threadIdx.x;
  if (i >= n8) return;
  const float4* p = (const float4*)in;
  float4 a = p[2*i], b = p[2*i+1];
  union { bf16 h[8]; uint4 u; } r;
  r.h[0] = (bf16)a.x; r.h[1] = (bf16)a.y; r.h[2] = (bf16)a.z; r.h[3] = (bf16)a.w;
  r.h[4] = (bf16)b.x; r.h[5] = (bf16)b.y; r.h[6] = (bf16)b.z; r.h[7] = (bf16)b.w;
  ((uint4*)out)[i] = r.u;
}

// ---------------- GEMM core 128x128: C = A @ B^T ----------------------
#define BM 128
#define BN 128
#define BK 32
#define NKI (EMBED/BK)   // 32

__device__ __forceinline__ void gemm_core(
    const bf16* __restrict__ A, const bf16* __restrict__ W,
    int m0, int n0, bf16* Al, bf16* Bl, f32x4 (&acc)[4][4])
{
  const int tid  = threadIdx.x;
  const int lane = tid & 63, wid = tid >> 6;
  const int quad = lane >> 4, l16 = lane & 15;
  const int wm = wid >> 1, wn = wid & 1;

  const int R = tid >> 2, Cc = tid & 3;
  const int gcol = (Cc ^ ((R >> 1) & 3)) * 8;          // swizzled source column
  const bf16* Ag = A + (size_t)(m0 + R) * EMBED + gcol;
  const bf16* Bg = W + (size_t)(n0 + R) * EMBED + gcol;
  bf16* AlW = Al + wid * 512;                          // wave's 1KB chunk
  bf16* BlW = Bl + wid * 512;

  g2l16(Ag, AlW);                      g2l16(Ag + (size_t)64*EMBED, AlW + 2048);
  g2l16(Bg, BlW);                      g2l16(Bg + (size_t)64*EMBED, BlW + 2048);
  __syncthreads();

  for (int ki = 0; ki < NKI; ++ki) {
    const int cur = ki & 1;
    if (ki + 1 < NKI) {
      const int nb = cur ^ 1;
      const int k0 = (ki + 1) * BK;
      g2l16(Ag + k0, AlW + nb*4096);
      g2l16(Ag + (size_t)64*EMBED + k0, AlW + nb*4096 + 2048);
      g2l16(Bg + k0, BlW + nb*4096);
      g2l16(Bg + (size_t)64*EMBED + k0, BlW + nb*4096 + 2048);
    }
    const bf16* Ac = Al + cur*4096;
    const bf16* Bc = Bl + cur*4096;
    bf16x8 af[4], bg[4];
#pragma unroll
    for (int i = 0; i < 4; ++i) {
      int ra = wm*64 + i*16 + l16;
      af[i] = *(const bf16x8*)(Ac + ra*32 + ((quad ^ ((ra>>1)&3))*8));
      int rb = wn*64 + i*16 + l16;
      bg[i] = *(const bf16x8*)(Bc + rb*32 + ((quad ^ ((rb>>1)&3))*8));
    }
#pragma unroll
    for (int i = 0; i < 4; ++i)
#pragma unroll
      for (int j = 0; j < 4; ++j)
        acc[i][j] = MFMA(af[i], bg[j], acc[i][j]);
    __syncthreads();
  }
}

// QKV fused: blockIdx.z selects {Q,K,V}. Q scaled by log2(e)/8.
// z==2 computes V^T DIRECTLY: C[dim][token] = Wv @ Xv^T, stored
// pi-permuted per 64-token tile: pos = (loc&15)*4 + (loc>>4).
__global__ __launch_bounds__(256) void qkv_kernel(
    const bf16* __restrict__ Xq, const bf16* __restrict__ Xk, const bf16* __restrict__ Xv,
    const bf16* __restrict__ Wq, const bf16* __restrict__ Wk, const bf16* __restrict__ Wv,
    const float* __restrict__ bq, const float* __restrict__ bk, const float* __restrict__ bv,
    bf16* __restrict__ Qp, bf16* __restrict__ Kp, bf16* __restrict__ VTg)
{
  __shared__ bf16 Al[2*BM*BK];
  __shared__ bf16 Bl[2*BN*BK];
  const int z = blockIdx.z;
  // z<2: A=X (rows=tokens m), B=W (rows=out-dims n)
  // z=2: A=Wv (rows=out-dims m), B=Xv (rows=tokens n)  -> C = V^T
  const bf16* A = z==0 ? Xq : z==1 ? Xk : Wv;
  const bf16* W = z==0 ? Wq : z==1 ? Wk : Xv;
  const float* bias = z==0 ? bq : z==1 ? bk : bv;
  const float scale = (z==0) ? QSCALE : 1.0f;
  const int m0 = (z < 2) ? blockIdx.y * BM : blockIdx.x * BM;  // z=2: dims (8 blocks)
  const int n0 = (z < 2) ? blockIdx.x * BN : blockIdx.y * BN;  // z=2: tokens (32 blocks)

  f32x4 acc[4][4] = {};
  gemm_core(A, W, m0, n0, Al, Bl, acc);

  const int lane = threadIdx.x & 63, wid = threadIdx.x >> 6;
  const int quad = lane >> 4, l16 = lane & 15;
  const int wm = wid >> 1, wn = wid & 1;

#pragma unroll
  for (int i = 0; i < 4; ++i) {
#pragma unroll
    for (int j = 0; j < 4; ++j) {
      int col = n0 + wn*64 + j*16 + l16;
      if (z < 2) {
        float bv2 = bias[col];
        bf16* outp = (z == 0) ? Qp : Kp;
#pragma unroll
        for (int r = 0; r < 4; ++r) {
          int row = m0 + wm*64 + i*16 + quad*4 + r;
          outp[(size_t)row*EMBED + col] = (bf16)((acc[i][j][r] + bv2) * scale);
        }
      } else {
        // row = output dim e, col = global token t
        int t  = col;
        int bb = t >> 11, ss = t & (SEQ-1);
        int tile = ss >> 6;
        int ppos = l16*4 + (j & 3);   // pi((j&3)*16 + l16)
#pragma unroll
        for (int r = 0; r < 4; ++r) {
          int e = m0 + wm*64 + i*16 + quad*4 + r;
          int hh = e >> 6, dd = e & (HD-1);
          VTg[(((size_t)bb*NHEAD + hh)*HD + dd)*SEQ + tile*64 + ppos]
              = (bf16)(acc[i][j][r] + bias[e]);
        }
      }
    }
  }
}

// ---------------- O-projection: 128x64 tiles, fp32 out ----------------
__global__ __launch_bounds__(256) void oproj_kernel(
    const bf16* __restrict__ Ctx, const bf16* __restrict__ Wo,
    const float* __restrict__ bo, float* __restrict__ out)
{
  __shared__ bf16 Al[2*128*32];   // 2 x 8KB
  __shared__ bf16 Bl[2*64*32];    // 2 x 4KB
  const int tid  = threadIdx.x;
  const int lane = tid & 63, wid = tid >> 6;
  const int quad = lane >> 4, l16 = lane & 15;
  const int m0 = blockIdx.y * 128, n0 = blockIdx.x * 64;

  const int R = tid >> 2, Cc = tid & 3;
  const int gcol = (Cc ^ ((R >> 1) & 3)) * 8;
  const bf16* Ag = Ctx + (size_t)(m0 + R) * EMBED + gcol;
  const bf16* Bg = Wo  + (size_t)(n0 + R) * EMBED + gcol;
  bf16* AlW = Al + wid * 512;
  bf16* BlW = Bl + wid * 512;

  g2l16(Ag, AlW);  g2l16(Ag + (size_t)64*EMBED, AlW + 2048);
  g2l16(Bg, BlW);
  __syncthreads();

  f32x4 acc[2][4] = {};
  for (int ki = 0; ki < NKI; ++ki) {
    const int cur = ki & 1;
    if (ki + 1 < NKI) {
      const int nb = cur ^ 1;
      const int k0 = (ki + 1) * BK;
      g2l16(Ag + k0, AlW + nb*4096);
      g2l16(Ag + (size_t)64*EMBED + k0, AlW + nb*4096 + 2048);
      g2l16(Bg + k0, BlW + nb*2048);
    }
    const bf16* Ac = Al + cur*4096;
    const bf16* Bc = Bl + cur*2048;
    bf16x8 af[2], bg[4];
#pragma unroll
    for (int u = 0; u < 2; ++u) {
      int ra = wid*32 + u*16 + l16;
      af[u] = *(const bf16x8*)(Ac + ra*32 + ((quad ^ ((ra>>1)&3))*8));
    }
#pragma unroll
    for (int j = 0; j < 4; ++j) {
      int rb = j*16 + l16;
      bg[j] = *(const bf16x8*)(Bc + rb*32 + ((quad ^ ((rb>>1)&3))*8));
    }
#pragma unroll
    for (int u = 0; u < 2; ++u)
#pragma unroll
      for (int j = 0; j < 4; ++j)
        acc[u][j] = MFMA(af[u], bg[j], acc[u][j]);
    __syncthreads();
  }

#pragma unroll
  for (int u = 0; u < 2; ++u)
#pragma unroll
    for (int j = 0; j < 4; ++j) {
      int col = n0 + j*16 + l16;
      float bv = bo[col];
#pragma unroll
      for (int r = 0; r < 4; ++r) {
        int row = m0 + wid*32 + u*16 + quad*4 + r;
        out[(size_t)row*EMBED + col] = (acc[u][j][r] + bv);
      }
    }
}

// ---------------- flash attention, software-pipelined -----------------
// 512 threads = 8 waves x 16 q-rows (128-row q-tile); 64-key tiles.
// Iteration i: prefetch(i+1) | QK+exp2(i) | PV(i-1) — the two compute
// stages are data-independent, breaking the per-tile serial chain.
// K double-buffered, V triple-buffered, P (wave-private) double-buffered.
#define NT  (SEQ/64)
#define PST 72

__global__ __launch_bounds__(512, 4) void attn_kernel(
    const bf16* __restrict__ Qp, const bf16* __restrict__ Kp, const bf16* __restrict__ VT,
    const int* __restrict__ pmask, bf16* __restrict__ Ctx)
{
  __shared__ __align__(16) bf16 Kt[2][64*64];     // 16 KB
  __shared__ __align__(16) bf16 Vt[3][64*64];     // 24 KB
  __shared__ __align__(16) bf16 Pl[2][8][16*PST]; // 36.9 KB

  const int qt = blockIdx.x, h = blockIdx.y, b = blockIdx.z;
  const int tid = threadIdx.x, lane = tid & 63, wid = tid >> 6;
  const int quad = lane >> 4, l16 = lane & 15;
  const int qrow0 = qt*128 + wid*16;

  const size_t qoff = (size_t)(b*SEQ + qrow0 + l16)*EMBED + h*HD;
  bf16x8 qf0 = *(const bf16x8*)(Qp + qoff + quad*8);
  bf16x8 qf1 = *(const bf16x8*)(Qp + qoff + 32 + quad*8);

  int qm[4];
#pragma unroll
  for (int r = 0; r < 4; ++r) qm[r] = pmask[b*SEQ + qrow0 + quad*4 + r];

  bf16 onev = (bf16)1.0f;
  bf16x8 ones = {onev, onev, onev, onev, onev, onev, onev, onev};

  const bf16* Kg  = Kp + (size_t)b*SEQ*EMBED + h*HD;
  const bf16* VTg = VT + (size_t)(b*NHEAD + h)*HD*SEQ;

  const int R = tid >> 3;                 // 0..63 (key idx for K, dim for V)
  const int Cc = tid & 7;
  const int scol = (Cc ^ (R & 7)) * 8;    // swizzled source column

  f32x4 o[4] = {};
  f32x4 lacc = {};

#define STAGE_K(kt, buf) g2l16(Kg + (size_t)((kt)*64 + R)*EMBED + scol, &Kt[buf][0] + wid*512)
#define STAGE_V(kt, buf) g2l16(VTg + (size_t)R*SEQ + (kt)*64 + scol,    &Vt[buf][0] + wid*512)

  STAGE_K(0, 0);
  STAGE_V(0, 0);
  __syncthreads();

  for (int kt = 0; kt < NT; ++kt) {
    if (kt + 1 < NT) {                       // prefetch tile kt+1
      STAGE_K(kt + 1, (kt + 1) & 1);
      STAGE_V(kt + 1, (kt + 1) % 3);
    }

    // ---- QK^T(kt) + mask + exp2 ----
    const bf16* Kc = &Kt[kt & 1][0];
    f32x4 sg[4];
#pragma unroll
    for (int g = 0; g < 4; ++g) {
      int ra = g*16 + l16, sa = ra & 7;
      bf16x8 kfa = *(const bf16x8*)(Kc + ra*64 + ((quad     ^ sa)*8));
      bf16x8 kfb = *(const bf16x8*)(Kc + ra*64 + (((quad+4) ^ sa)*8));
      int km = pmask[b*SEQ + kt*64 + g*16 + l16];
      f32x4 s = {};
      s = MFMA(qf0, kfa, s);
      s = MFMA(qf1, kfb, s);
#pragma unroll
      for (int r = 0; r < 4; ++r) sg[g][r] = km ? EXP2(s[r]) : 0.0f;
    }

    // ---- PV(kt-1): independent of the QK stage above ----
    if (kt > 0) {
      const bf16* Vc = &Vt[(kt - 1) % 3][0];
      bf16* Pw = &Pl[(kt - 1) & 1][wid][0];
      bf16x8 pf0 = *(const bf16x8*)(Pw + l16*PST + quad*8);
      bf16x8 pf1 = *(const bf16x8*)(Pw + l16*PST + 32 + quad*8);
      lacc = MFMA(pf0, ones, lacc);
      lacc = MFMA(pf1, ones, lacc);
#pragma unroll
      for (int t = 0; t < 4; ++t) {
        int rd = t*16 + l16, sd = rd & 7;
        bf16x8 vf0 = *(const bf16x8*)(Vc + rd*64 + ((quad     ^ sd)*8));
        bf16x8 vf1 = *(const bf16x8*)(Vc + rd*64 + (((quad+4) ^ sd)*8));
        o[t] = MFMA(pf0, vf0, o[t]);
        o[t] = MFMA(pf1, vf1, o[t]);
      }
    }

    // ---- pi-packed P(kt) store: position l16*4+g, one b64 per r ----
    {
      bf16* Pw = &Pl[kt & 1][wid][0];
#pragma unroll
      for (int r = 0; r < 4; ++r) {
        union { bf16 h[4]; uint2 uu; } pk;
#pragma unroll
        for (int g = 0; g < 4; ++g) pk.h[g] = (bf16)sg[g][r];
        *(uint2*)(Pw + (quad*4 + r)*PST + l16*4) = pk.uu;
      }
    }
    __syncthreads();   // prefetch landed + everyone done with Kt[kt&1]
  }

  // ---- epilogue PV(NT-1) ----
  {
    const bf16* Vc = &Vt[(NT - 1) % 3][0];
    bf16* Pw = &Pl[(NT - 1) & 1][wid][0];
    bf16x8 pf0 = *(const bf16x8*)(Pw + l16*PST + quad*8);
    bf16x8 pf1 = *(const bf16x8*)(Pw + l16*PST + 32 + quad*8);
    lacc = MFMA(pf0, ones, lacc);
    lacc = MFMA(pf1, ones, lacc);
#pragma unroll
    for (int t = 0; t < 4; ++t) {
      int rd = t*16 + l16, sd = rd & 7;
      bf16x8 vf0 = *(const bf16x8*)(Vc + rd*64 + ((quad     ^ sd)*8));
      bf16x8 vf1 = *(const bf16x8*)(Vc + rd*64 + (((quad+4) ^ sd)*8));
      o[t] = MFMA(pf0, vf0, o[t]);
      o[t] = MFMA(pf1, vf1, o[t]);
    }
  }

  float inv[4];
#pragma unroll
  for (int r = 0; r < 4; ++r)
    inv[r] = (qm[r] && lacc[r] > 0.f) ? 1.0f / lacc[r] : 0.0f;

#pragma unroll
  for (int t = 0; t < 4; ++t)
#pragma unroll
    for (int r = 0; r < 4; ++r) {
      int row = b*SEQ + qrow0 + quad*4 + r;
      Ctx[(size_t)row*EMBED + h*HD + t*16 + l16] = (bf16)(o[t][r] * inv[r]);
    }
}

// ----------------------------------------------------------------------
extern "C" void kernel_launch(void* const* d_in, const int* in_sizes, int n_in,
                              void* d_out, int out_size, void* d_ws, size_t ws_size,
                              hipStream_t stream)
{
  const float* query = (const float*)d_in[0];
  const float* key   = (const float*)d_in[1];
  const float* value = (const float*)d_in[2];
  const int*   pm    = (const int*)d_in[3];
  const float* Wq = (const float*)d_in[4];
  const float* bq = (const float*)d_in[5];
  const float* Wk = (const float*)d_in[6];
  const float* bk = (const float*)d_in[7];
  const float* Wv = (const float*)d_in[8];
  const float* bv = (const float*)d_in[9];
  const float* Wo = (const float*)d_in[10];
  const float* bo = (const float*)d_in[11];
  float* out = (float*)d_out;

  const size_t SZ_X = (size_t)MROWS * EMBED;   // 4M elems
  const size_t SZ_W = (size_t)EMBED * EMBED;   // 1M elems

  bf16* p   = (bf16*)d_ws;
  bf16* Xq  = p; p += SZ_X;
  bf16* Xk  = p; p += SZ_X;
  bf16* Xv  = p; p += SZ_X;
  bf16* Wqb = p; p += SZ_W;
  bf16* Wkb = p; p += SZ_W;
  bf16* Wvb = p; p += SZ_W;
  bf16* Wob = p; p += SZ_W;
  bf16* Qp  = p; p += SZ_X;
  bf16* Kp  = p; p += SZ_X;
  bf16* VTg = p; p += SZ_X;   // V^T: [b][h][d][pi-ordered s]
  bf16* Ctx = p; p += SZ_X;

  dim3 gc((unsigned)(SZX8/256), 7);   // one dispatch for all 7 casts
  cast_all<<<gc, 256, 0, stream>>>(query, key, value, Wq, Wk, Wv, Wo,
                                   Xq, Xk, Xv, Wqb, Wkb, Wvb, Wob);

  dim3 gq(EMBED/BN, MROWS/BM, 3);   // (8, 32, 3)
  qkv_kernel<<<gq, 256, 0, stream>>>(Xq, Xk, Xv, Wqb, Wkb, Wvb, bq, bk, bv, Qp, Kp, VTg);

  dim3 ga(SEQ/128, NHEAD, BATCH);   // (16, 16, 2) = 512 blocks
  attn_kernel<<<ga, 512, 0, stream>>>(Qp, Kp, VTg, pm, Ctx);

  dim3 gg(EMBED/64, MROWS/128);     // (16, 32) = 512 blocks
  oproj_kernel<<<gg, 256, 0, stream>>>(Ctx, Wob, bo, out);
}